// Round 2
// baseline (1092.379 us; speedup 1.0000x reference)
//
#include <hip/hip_runtime.h>

// MoE fused kernel, MI355X gfx950 — Round 5: barrier-free loop + explicit prefetch.
// Shapes: B=65536, D=512, C=101, E=8, H=256.
// out[b,c] = sum_{e,h} g[b,e]*relu(x@W1+b1)[b,e,h]*W2[e,h,c] + sum_e g[b,e]*b2[e,c]
// g = softmax(x@Wg+bg), gate logits folded into layer1 GEMM as cols 2048..2055.
//
// R5: R4 post-mortem — spills fixed (WRITE 460->26MB) but dur 343->393:
// VGPR_Count=68 means zero load prefetch (every L2 b-frag load latency-exposed
// into its MFMA), and 16 in-loop barriers serialized the 4 waves. R5 keeps
// R4's Mtile=32 / 3 blocks/CU geometry but: (1) layer2 back to K-sliced
// wave-private hAw (R3-style, ZERO nt-loop barriers; end reduction only),
// acc2[2][7]=56 regs (ct=7 all-padding, skipped) -> no spill; (2) explicit
// double-buffered b-frag prefetch bA/bB in layer1 (named bufs, static idx) to
// force in-flight loads. Budget ~155 VGPR under launch_bounds(256,3) cap 170.
//
// MFMA layouts (m89/m120-verified):
//   A: A[m][k], m=lane&15, k=(lane>>4)*8+j (j=0..7)
//   B: B[k][n], n=lane&15, k=(lane>>4)*8+j
//   C/D: col=lane&15, row=(lane>>4)*4+reg

typedef __attribute__((ext_vector_type(8))) short short8x;
typedef __attribute__((ext_vector_type(4))) float float4x;

#define C_DIM 101

__device__ __forceinline__ unsigned short f2bf(float f) {
  unsigned int u = __builtin_bit_cast(unsigned int, f);
  u += 0x7fffu + ((u >> 16) & 1u);     // round-to-nearest-even
  return (unsigned short)(u >> 16);
}

// ---- W1 (+Wg) -> bf16, B-frag packed: frag = ntile*16+kf ; elem = frag*512 + lane*8 + j
__global__ void conv_w1(const float* __restrict__ W1, const float* __restrict__ Wg,
                        unsigned short* __restrict__ out) {
  int s = blockIdx.x * blockDim.x + threadIdx.x;   // slot = frag*64 + lane
  int l = s & 63;
  int frag = s >> 6;
  int kf = frag & 15;
  int ntile = frag >> 4;
  int n = (ntile << 4) | (l & 15);
  int k = (kf << 5) | ((l >> 4) << 3);
  short8x v;
#pragma unroll
  for (int j = 0; j < 8; ++j) {
    int kk = k + j;
    float f;
    if (n < 2048)      f = W1[((size_t)(n >> 8) * 512 + kk) * 256 + (n & 255)];
    else if (n < 2056) f = Wg[(size_t)kk * 8 + (n - 2048)];
    else               f = 0.f;
    v[j] = (short)f2bf(f);
  }
  *(short8x*)(out + (size_t)s * 8) = v;
}

// ---- W2 -> bf16, B-frag packed: frag = ntile*64+kf ; ntile 0..7, kf 0..63 (K=2048)
__global__ void conv_w2(const float* __restrict__ W2, unsigned short* __restrict__ out) {
  int s = blockIdx.x * blockDim.x + threadIdx.x;
  int l = s & 63;
  int frag = s >> 6;
  int kf = frag & 63;
  int ntile = frag >> 6;
  int c = (ntile << 4) | (l & 15);
  int k = (kf << 5) | ((l >> 4) << 3);
  short8x v;
#pragma unroll
  for (int j = 0; j < 8; ++j) {
    int kk = k + j;                       // e = kk>>8, h = kk&255
    float f = (c < C_DIM) ? W2[((size_t)(kk >> 8) * 256 + (kk & 255)) * C_DIM + c] : 0.f;
    v[j] = (short)f2bf(f);
  }
  *(short8x*)(out + (size_t)s * 8) = v;
}

// ---- fused main kernel: 32 rows/block, 256 threads (4 waves), 3 blocks/CU
__global__ __launch_bounds__(256, 3) void moe_main(
    const float* __restrict__ x, const float* __restrict__ b1,
    const float* __restrict__ b2, const float* __restrict__ bg,
    const unsigned short* __restrict__ W1bf, const unsigned short* __restrict__ W2bf,
    float* __restrict__ out) {
  __shared__ unsigned short xA[32 * 512];   // 32 KB: x A-frags [mt*16+kf][lane*8+j]
  __shared__ unsigned short hA[4 * 2048];   // 16 KB: 4 waves x wave-private 4 frags
  __shared__ float gt[8 * 32];              //  1 KB: gates^T [e][row]
  float* graw = (float*)hA;                 // raw gate logits [32][8]; pre-loop only
  float* red  = (float*)xA;                 // end-phase reduction; reuses xA

  const int tid = threadIdx.x;
  const int w = tid >> 6;     // wave 0..3
  const int l = tid & 63;     // lane
  const int quad = l >> 4;
  const int p = l & 15;
  const int r0 = blockIdx.x * 32;
  unsigned short* hAw = hA + w * 2048;      // wave-private: 4 frags x 512 shorts

  // ---- stage x -> bf16 A-frag LDS (coalesced float4 x2 reads, b128 LDS writes)
#pragma unroll
  for (int it = 0; it < 8; ++it) {
    int g = tid + it * 256;            // m = g>>6 (0..31), k0 = (g&63)*8
    int m = g >> 6;
    int k0 = (g & 63) << 3;
    const float* src = x + (size_t)(r0 + m) * 512 + k0;
    float4 f0 = *(const float4*)src;
    float4 f1 = *(const float4*)(src + 4);
    short8x v;
    v[0] = (short)f2bf(f0.x); v[1] = (short)f2bf(f0.y);
    v[2] = (short)f2bf(f0.z); v[3] = (short)f2bf(f0.w);
    v[4] = (short)f2bf(f1.x); v[5] = (short)f2bf(f1.y);
    v[6] = (short)f2bf(f1.z); v[7] = (short)f2bf(f1.w);
    int mt = m >> 4;
    int kfrag = k0 >> 5;
    int lane = (((k0 >> 3) & 3) << 4) | (m & 15);
    *(short8x*)&xA[(size_t)(((mt << 4) | kfrag) * 64 + lane) * 8] = v;
  }
  __syncthreads();

  // ---- gate logits: waves 0,1 each do one 16-row tile x 16 gate cols (ntile 128)
  if (w < 2) {
    float4x acc = {0.f, 0.f, 0.f, 0.f};
#pragma unroll 2
    for (int kf = 0; kf < 16; ++kf) {
      short8x a = *(const short8x*)&xA[(size_t)((w * 16 + kf) * 64 + l) * 8];
      short8x b = *(const short8x*)(W1bf + ((size_t)(128 * 16 + kf) * 512 + l * 8));
      acc = __builtin_amdgcn_mfma_f32_16x16x32_bf16(a, b, acc, 0, 0, 0);
    }
    if (p < 8) {
      float bgv = bg[p];
#pragma unroll
      for (int r = 0; r < 4; ++r)
        graw[(w * 16 + quad * 4 + r) * 8 + p] = acc[r] + bgv;
    }
  }
  __syncthreads();
  // softmax over E=8 per row, fp32; write transposed gt[e][row]
  if (tid < 32) {
    float v[8], mx = -1e30f;
#pragma unroll
    for (int e = 0; e < 8; ++e) { v[e] = graw[tid * 8 + e]; mx = fmaxf(mx, v[e]); }
    float s = 0.f;
#pragma unroll
    for (int e = 0; e < 8; ++e) { v[e] = expf(v[e] - mx); s += v[e]; }
    float inv = 1.f / s;
#pragma unroll
    for (int e = 0; e < 8; ++e) gt[e * 32 + tid] = v[e] * inv;
  }
  __syncthreads();   // graw (hA alias) reads done before first hAw write

  // ---- main loop over 8 experts (nt = e): ZERO barriers inside
  float4x zero = {0.f, 0.f, 0.f, 0.f};
  float4x acc2[2][7];                    // layer2 K-sliced partial; ct=7 all-pad, skipped
#pragma unroll
  for (int mt = 0; mt < 2; ++mt)
#pragma unroll
    for (int ct = 0; ct < 7; ++ct) acc2[mt][ct] = zero;

  for (int nt = 0; nt < 8; ++nt) {
    // layer1: wave w covers h-cols [nt*256 + w*64, +64), all 32 rows.
    // Explicit double-buffered b-frag prefetch (bA/bB), 1 kf ahead.
    float4x acc1[2][4];                  // [mt][nc]
#pragma unroll
    for (int mt = 0; mt < 2; ++mt)
#pragma unroll
      for (int nc = 0; nc < 4; ++nc) acc1[mt][nc] = zero;

    const unsigned short* __restrict__ bp =
        W1bf + ((size_t)(nt * 16 + w * 4) * 16) * 512 + (size_t)l * 8;
    // nc stride = 16 frags * 512 = 8192 shorts; kf stride = 512 shorts
    short8x bA[4], bB[4];
#pragma unroll
    for (int nc = 0; nc < 4; ++nc) bA[nc] = *(const short8x*)(bp + nc * 8192);

#pragma unroll
    for (int kf = 0; kf < 16; kf += 2) {
      // prefetch kf+1 into bB
#pragma unroll
      for (int nc = 0; nc < 4; ++nc)
        bB[nc] = *(const short8x*)(bp + nc * 8192 + (kf + 1) * 512);
      short8x a0 = *(const short8x*)&xA[(size_t)((0 * 16 + kf) * 64 + l) * 8];
      short8x a1 = *(const short8x*)&xA[(size_t)((1 * 16 + kf) * 64 + l) * 8];
#pragma unroll
      for (int nc = 0; nc < 4; ++nc) {
        acc1[0][nc] = __builtin_amdgcn_mfma_f32_16x16x32_bf16(a0, bA[nc], acc1[0][nc], 0, 0, 0);
        acc1[1][nc] = __builtin_amdgcn_mfma_f32_16x16x32_bf16(a1, bA[nc], acc1[1][nc], 0, 0, 0);
      }
      // prefetch kf+2 into bA (skipped on last pair)
      if (kf + 2 < 16) {
#pragma unroll
        for (int nc = 0; nc < 4; ++nc)
          bA[nc] = *(const short8x*)(bp + nc * 8192 + (kf + 2) * 512);
      }
      short8x a2 = *(const short8x*)&xA[(size_t)((0 * 16 + kf + 1) * 64 + l) * 8];
      short8x a3 = *(const short8x*)&xA[(size_t)((1 * 16 + kf + 1) * 64 + l) * 8];
#pragma unroll
      for (int nc = 0; nc < 4; ++nc) {
        acc1[0][nc] = __builtin_amdgcn_mfma_f32_16x16x32_bf16(a2, bB[nc], acc1[0][nc], 0, 0, 0);
        acc1[1][nc] = __builtin_amdgcn_mfma_f32_16x16x32_bf16(a3, bB[nc], acc1[1][nc], 0, 0, 0);
      }
    }

    // gates for this expert
    float4x gv0 = *(const float4x*)&gt[nt * 32 + 0  + quad * 4];
    float4x gv1 = *(const float4x*)&gt[nt * 32 + 16 + quad * 4];

    // epilogue: +b1, relu, *gate, bf16 -> WAVE-PRIVATE hAw (C->A transpose), no barrier
#pragma unroll
    for (int nc = 0; nc < 4; ++nc) {
      int cw = w * 64 + nc * 16 + p;     // global col within nt-tile (0..255)
      float b1v = b1[nt * 256 + cw];
      int koff = ((nc & 1) << 4) | p;    // col within 32-col K-frag
      int c5 = nc >> 1;                  // which of wave's 2 K-frags
      int jj = koff & 7;
      int ldbase = (koff >> 3) << 4;     // chunk*16
#pragma unroll
      for (int mt = 0; mt < 2; ++mt) {
#pragma unroll
        for (int r = 0; r < 4; ++r) {
          float hv = fmaxf(acc1[mt][nc][r] + b1v, 0.f) * (mt ? gv1[r] : gv0[r]);
          hAw[(c5 * 2 + mt) * 512 + (ldbase + quad * 4 + r) * 8 + jj] = f2bf(hv);
        }
      }
    }

    // layer2: wave's K-slice (2 K-frags = its 64 h-cols) x 7 ct tiles, wave-private
    const unsigned short* __restrict__ bp2 =
        W2bf + (size_t)(nt * 8 + w * 2) * 512 + (size_t)l * 8;
    // frag = ct*64 + nt*8 + w*2 + c5 -> offset (ct*64 + c5)*512 from bp2
#pragma unroll
    for (int c5 = 0; c5 < 2; ++c5) {
      short8x a0 = *(const short8x*)&hAw[(size_t)((c5 * 2 + 0) * 64 + l) * 8];
      short8x a1 = *(const short8x*)&hAw[(size_t)((c5 * 2 + 1) * 64 + l) * 8];
#pragma unroll
      for (int ct = 0; ct < 7; ++ct) {
        short8x b = *(const short8x*)(bp2 + ((size_t)ct * 64 + c5) * 512);
        acc2[0][ct] = __builtin_amdgcn_mfma_f32_16x16x32_bf16(a0, b, acc2[0][ct], 0, 0, 0);
        acc2[1][ct] = __builtin_amdgcn_mfma_f32_16x16x32_bf16(a1, b, acc2[1][ct], 0, 0, 0);
      }
    }
  }

  // ---- end: cross-wave reduction of K-sliced acc2 (red reuses xA), + bias, store
  // wave w owns ct in {2w, 2w+1} (wave 3 owns only ct=6); 3 contributors per ct
#pragma unroll
  for (int mt = 0; mt < 2; ++mt) {
    __syncthreads();                    // mt=0: all waves past last xA read; mt=1: reads done
#pragma unroll
    for (int ct = 0; ct < 7; ++ct) {
      int owner = ct >> 1;
      if (owner != w) {
        int s = w - (w > owner ? 1 : 0);   // 0..2
        *(float4x*)&red[((ct * 3 + s) * 64 + l) * 4] = acc2[mt][ct];
      }
    }
    __syncthreads();
#pragma unroll
    for (int ct2 = 0; ct2 < 2; ++ct2) {
      int ct = w * 2 + ct2;
      if (ct < 7) {
        float4x sum = acc2[mt][ct];
#pragma unroll
        for (int s = 0; s < 3; ++s)
          sum += *(const float4x*)&red[((ct * 3 + s) * 64 + l) * 4];
        int c = ct * 16 + p;
        if (c < C_DIM) {
#pragma unroll
          for (int r = 0; r < 4; ++r) {
            int row = mt * 16 + quad * 4 + r;
            float bias = 0.f;
#pragma unroll
            for (int e = 0; e < 8; ++e) bias += gt[e * 32 + row] * b2[e * C_DIM + c];
            out[(size_t)(r0 + row) * C_DIM + c] = sum[r] + bias;
          }
        }
      }
    }
  }
}

extern "C" void kernel_launch(void* const* d_in, const int* in_sizes, int n_in,
                              void* d_out, int out_size, void* d_ws, size_t ws_size,
                              hipStream_t stream) {
  const float* x  = (const float*)d_in[0];
  const float* W1 = (const float*)d_in[1];
  const float* b1 = (const float*)d_in[2];
  const float* W2 = (const float*)d_in[3];
  const float* b2 = (const float*)d_in[4];
  const float* Wg = (const float*)d_in[5];
  const float* bg = (const float*)d_in[6];
  float* out = (float*)d_out;

  unsigned short* W1bf = (unsigned short*)d_ws;
  unsigned short* W2bf = (unsigned short*)((char*)d_ws + (size_t)129 * 16 * 512 * 2);

  conv_w1<<<516, 256, 0, stream>>>(W1, Wg, W1bf);   // 129*16*64 slots
  conv_w2<<<128, 256, 0, stream>>>(W2, W2bf);       // 8*64*64 slots
  moe_main<<<2048, 256, 0, stream>>>(x, b1, b2, bg, W1bf, W2bf, out);
}

// Round 4
// 403.269 us; speedup vs baseline: 2.7088x; 2.7088x over previous
//
#include <hip/hip_runtime.h>

// MoE fused kernel, MI355X gfx950 — Round 7 (= R6 resubmit; R6 bench was an
// infra failure: "container failed twice", no counters, no kernel error).
// 8-wave blocks, ct-owned layer2, expert-paired barriers, slim registers.
// Shapes: B=65536, D=512, C=101, E=8, H=256.
// out[b,c] = sum_{e,h} g[b,e]*relu(x@W1+b1)[b,e,h]*W2[e,h,c] + sum_e g[b,e]*b2[e,c]
// g = softmax(x@Wg+bg), gate logits folded into layer1 GEMM as cols 2048..2055.
//
// R5 post-mortem — acc2[2][7]=56 regs K-sliced across nt + layer1 prefetch
// blew the 170-reg cap -> 1.2GB spill writes (FETCH 1.7GB), 975us. Structural
// rule learned: layer2 accumulator must be ct-OWNED (8-16 regs), never K-sliced
// across the nt loop. R6 = R4's ct-owned layer2 + fixes for R4's defects:
// (1) 512-thread blocks, LDS 65KB -> 2 blocks/CU = 16 waves/CU (R4: 12) so
// barrier stalls are absorbed by the co-resident block; (2) hA holds TWO
// experts -> 2 barriers per expert-PAIR (8 in-loop, R4 had 16), with
// layer1(e1) between hA[0] writes and the barrier; (3) explicit 1-kf-ahead b
// prefetch (2 frags, 16 regs). Tally ~90-100 regs under launch_bounds(512,4)
// cap 128 -> no spills. Known ceiling: Mtile=32 puts layer1 at 512 B/MFMA from
// L2 vs 272 supply -> ~150us L2 floor; Mtile=64 restructure is next if we
// approach it.
//
// MFMA layouts (m89/m120-verified):
//   A: A[m][k], m=lane&15, k=(lane>>4)*8+j (j=0..7)
//   B: B[k][n], n=lane&15, k=(lane>>4)*8+j
//   C/D: col=lane&15, row=(lane>>4)*4+reg

typedef __attribute__((ext_vector_type(8))) short short8x;
typedef __attribute__((ext_vector_type(4))) float float4x;

#define C_DIM 101

__device__ __forceinline__ unsigned short f2bf(float f) {
  unsigned int u = __builtin_bit_cast(unsigned int, f);
  u += 0x7fffu + ((u >> 16) & 1u);     // round-to-nearest-even
  return (unsigned short)(u >> 16);
}

// ---- W1 (+Wg) -> bf16, B-frag packed: frag = ntile*16+kf ; elem = frag*512 + lane*8 + j
__global__ void conv_w1(const float* __restrict__ W1, const float* __restrict__ Wg,
                        unsigned short* __restrict__ out) {
  int s = blockIdx.x * blockDim.x + threadIdx.x;   // slot = frag*64 + lane
  int l = s & 63;
  int frag = s >> 6;
  int kf = frag & 15;
  int ntile = frag >> 4;
  int n = (ntile << 4) | (l & 15);
  int k = (kf << 5) | ((l >> 4) << 3);
  short8x v;
#pragma unroll
  for (int j = 0; j < 8; ++j) {
    int kk = k + j;
    float f;
    if (n < 2048)      f = W1[((size_t)(n >> 8) * 512 + kk) * 256 + (n & 255)];
    else if (n < 2056) f = Wg[(size_t)kk * 8 + (n - 2048)];
    else               f = 0.f;
    v[j] = (short)f2bf(f);
  }
  *(short8x*)(out + (size_t)s * 8) = v;
}

// ---- W2 -> bf16, B-frag packed: frag = ntile*64+kf ; ntile 0..7, kf 0..63 (K=2048)
__global__ void conv_w2(const float* __restrict__ W2, unsigned short* __restrict__ out) {
  int s = blockIdx.x * blockDim.x + threadIdx.x;
  int l = s & 63;
  int frag = s >> 6;
  int kf = frag & 63;
  int ntile = frag >> 6;
  int c = (ntile << 4) | (l & 15);
  int k = (kf << 5) | ((l >> 4) << 3);
  short8x v;
#pragma unroll
  for (int j = 0; j < 8; ++j) {
    int kk = k + j;                       // e = kk>>8, h = kk&255
    float f = (c < C_DIM) ? W2[((size_t)(kk >> 8) * 256 + (kk & 255)) * C_DIM + c] : 0.f;
    v[j] = (short)f2bf(f);
  }
  *(short8x*)(out + (size_t)s * 8) = v;
}

// ---- fused main kernel: 32 rows/block, 512 threads (8 waves), 2 blocks/CU
__global__ __launch_bounds__(512, 4) void moe_main(
    const float* __restrict__ x, const float* __restrict__ b1,
    const float* __restrict__ b2, const float* __restrict__ bg,
    const unsigned short* __restrict__ W1bf, const unsigned short* __restrict__ W2bf,
    float* __restrict__ out) {
  __shared__ unsigned short xA[32 * 512];   // 32 KB: x A-frags [mt*16+kf][lane*8+j]
  __shared__ unsigned short hA[32 * 512];   // 32 KB: 2 experts x 16 h' A-frags
  __shared__ float gt[8 * 32];              //  1 KB: gates^T [e][row]
  float* graw = (float*)hA;                 // raw gate logits [32][8]; pre-loop only

  const int tid = threadIdx.x;
  const int w = tid >> 6;     // wave 0..7
  const int l = tid & 63;     // lane
  const int quad = l >> 4;
  const int p = l & 15;
  const int r0 = blockIdx.x * 32;

  // ---- stage x -> bf16 A-frag LDS (coalesced float4 x2 reads, b128 LDS writes)
#pragma unroll
  for (int it = 0; it < 4; ++it) {
    int g = tid + it * 512;            // m = g>>6 (0..31), k0 = (g&63)*8
    int m = g >> 6;
    int k0 = (g & 63) << 3;
    const float* src = x + (size_t)(r0 + m) * 512 + k0;
    float4 f0 = *(const float4*)src;
    float4 f1 = *(const float4*)(src + 4);
    short8x v;
    v[0] = (short)f2bf(f0.x); v[1] = (short)f2bf(f0.y);
    v[2] = (short)f2bf(f0.z); v[3] = (short)f2bf(f0.w);
    v[4] = (short)f2bf(f1.x); v[5] = (short)f2bf(f1.y);
    v[6] = (short)f2bf(f1.z); v[7] = (short)f2bf(f1.w);
    int mt = m >> 4;
    int kfrag = k0 >> 5;
    int lane = (((k0 >> 3) & 3) << 4) | (m & 15);
    *(short8x*)&xA[(size_t)(((mt << 4) | kfrag) * 64 + lane) * 8] = v;
  }
  __syncthreads();

  // ---- gate logits: waves 0,1 each do one 16-row tile x 16 gate cols (ntile 128)
  if (w < 2) {
    float4x acc = {0.f, 0.f, 0.f, 0.f};
#pragma unroll 2
    for (int kf = 0; kf < 16; ++kf) {
      short8x a = *(const short8x*)&xA[(size_t)((w * 16 + kf) * 64 + l) * 8];
      short8x b = *(const short8x*)(W1bf + ((size_t)(128 * 16 + kf) * 512 + l * 8));
      acc = __builtin_amdgcn_mfma_f32_16x16x32_bf16(a, b, acc, 0, 0, 0);
    }
    if (p < 8) {
      float bgv = bg[p];
#pragma unroll
      for (int r = 0; r < 4; ++r)
        graw[(w * 16 + quad * 4 + r) * 8 + p] = acc[r] + bgv;
    }
  }
  __syncthreads();
  // softmax over E=8 per row, fp32; write transposed gt[e][row]
  if (tid < 32) {
    float v[8], mx = -1e30f;
#pragma unroll
    for (int e = 0; e < 8; ++e) { v[e] = graw[tid * 8 + e]; mx = fmaxf(mx, v[e]); }
    float s = 0.f;
#pragma unroll
    for (int e = 0; e < 8; ++e) { v[e] = expf(v[e] - mx); s += v[e]; }
    float inv = 1.f / s;
#pragma unroll
    for (int e = 0; e < 8; ++e) gt[e * 32 + tid] = v[e] * inv;
  }
  __syncthreads();   // graw (hA alias) reads done before first hA write

  // ---- main loop: 4 iterations, 2 experts each. acc2 = ct-owned full-K sum.
  float4x zero = {0.f, 0.f, 0.f, 0.f};
  float4x acc2[2];                       // [mt]; wave w owns output col-tile ct=w (w<7)
  acc2[0] = zero; acc2[1] = zero;

  for (int it = 0; it < 4; ++it) {
#pragma unroll
    for (int eo = 0; eo < 2; ++eo) {
      const int e = it * 2 + eo;
      // layer1: wave w covers h-cols [e*256 + w*32, +32), all 32 rows.
      float4x acc1[2][2];                // [mt][nc]
      acc1[0][0] = zero; acc1[0][1] = zero; acc1[1][0] = zero; acc1[1][1] = zero;

      const unsigned short* __restrict__ bp =
          W1bf + ((size_t)(e * 16 + w * 2) * 16) * 512 + (size_t)l * 8;
      // nc stride = 16 frags * 512 = 8192 shorts; kf stride = 512 shorts
      short8x bA0 = *(const short8x*)(bp);
      short8x bA1 = *(const short8x*)(bp + 8192);
      short8x bB0, bB1;
#pragma unroll
      for (int kf = 0; kf < 16; kf += 2) {
        bB0 = *(const short8x*)(bp + (kf + 1) * 512);
        bB1 = *(const short8x*)(bp + 8192 + (kf + 1) * 512);
        short8x a0 = *(const short8x*)&xA[(size_t)((0 * 16 + kf) * 64 + l) * 8];
        short8x a1 = *(const short8x*)&xA[(size_t)((1 * 16 + kf) * 64 + l) * 8];
        acc1[0][0] = __builtin_amdgcn_mfma_f32_16x16x32_bf16(a0, bA0, acc1[0][0], 0, 0, 0);
        acc1[1][0] = __builtin_amdgcn_mfma_f32_16x16x32_bf16(a1, bA0, acc1[1][0], 0, 0, 0);
        acc1[0][1] = __builtin_amdgcn_mfma_f32_16x16x32_bf16(a0, bA1, acc1[0][1], 0, 0, 0);
        acc1[1][1] = __builtin_amdgcn_mfma_f32_16x16x32_bf16(a1, bA1, acc1[1][1], 0, 0, 0);
        if (kf + 2 < 16) {
          bA0 = *(const short8x*)(bp + (kf + 2) * 512);
          bA1 = *(const short8x*)(bp + 8192 + (kf + 2) * 512);
        }
        short8x a2 = *(const short8x*)&xA[(size_t)((0 * 16 + kf + 1) * 64 + l) * 8];
        short8x a3 = *(const short8x*)&xA[(size_t)((1 * 16 + kf + 1) * 64 + l) * 8];
        acc1[0][0] = __builtin_amdgcn_mfma_f32_16x16x32_bf16(a2, bB0, acc1[0][0], 0, 0, 0);
        acc1[1][0] = __builtin_amdgcn_mfma_f32_16x16x32_bf16(a3, bB0, acc1[1][0], 0, 0, 0);
        acc1[0][1] = __builtin_amdgcn_mfma_f32_16x16x32_bf16(a2, bB1, acc1[0][1], 0, 0, 0);
        acc1[1][1] = __builtin_amdgcn_mfma_f32_16x16x32_bf16(a3, bB1, acc1[1][1], 0, 0, 0);
      }

      if (eo == 0) __syncthreads();      // BAR1: prev iteration's layer2 hA reads done

      // epilogue: +b1, relu, *gate(e), bf16 -> hA[eo] (C->A transpose)
      float4x gv0 = *(const float4x*)&gt[e * 32 + 0  + quad * 4];
      float4x gv1 = *(const float4x*)&gt[e * 32 + 16 + quad * 4];
#pragma unroll
      for (int nc = 0; nc < 2; ++nc) {
        int cw = w * 32 + nc * 16 + p;   // col within expert tile (0..255); kf2 = w
        float b1v = b1[e * 256 + cw];
        int jj = p & 7;
        int ldbase = ((nc * 2 + (p >> 3)) << 4);   // (koff>>3)*16, koff = nc*16+p
#pragma unroll
        for (int mt = 0; mt < 2; ++mt) {
#pragma unroll
          for (int r = 0; r < 4; ++r) {
            float hv = fmaxf(acc1[mt][nc][r] + b1v, 0.f) * (mt ? gv1[r] : gv0[r]);
            hA[(size_t)((eo * 16 + w * 2 + mt) * 512) + (ldbase + quad * 4 + r) * 8 + jj] =
                f2bf(hv);
          }
        }
      }
    }
    __syncthreads();                     // BAR2: both experts' h' published

    // layer2: wave w (<7) accumulates ct=w over both experts' K=512
    if (w < 7) {
      const unsigned short* __restrict__ bp2 =
          W2bf + ((size_t)(w * 64 + it * 16)) * 512 + (size_t)l * 8;
      // frag = w*64 + (it*2+eo)*8 + kk -> offset (eo*8+kk)*512 from bp2
#pragma unroll
      for (int eo = 0; eo < 2; ++eo) {
#pragma unroll
        for (int kk = 0; kk < 8; ++kk) {
          short8x a0 = *(const short8x*)&hA[(size_t)((eo * 16 + kk * 2 + 0) * 64 + l) * 8];
          short8x a1 = *(const short8x*)&hA[(size_t)((eo * 16 + kk * 2 + 1) * 64 + l) * 8];
          short8x b = *(const short8x*)(bp2 + (size_t)(eo * 8 + kk) * 512);
          acc2[0] = __builtin_amdgcn_mfma_f32_16x16x32_bf16(a0, b, acc2[0], 0, 0, 0);
          acc2[1] = __builtin_amdgcn_mfma_f32_16x16x32_bf16(a1, b, acc2[1], 0, 0, 0);
        }
      }
    }
  }

  // ---- epilogue: + gate-weighted b2, store. No cross-wave reduction.
  if (w < 7) {
    int c = w * 16 + p;
    if (c < C_DIM) {
#pragma unroll
      for (int mt = 0; mt < 2; ++mt) {
#pragma unroll
        for (int r = 0; r < 4; ++r) {
          int row = mt * 16 + quad * 4 + r;
          float bias = 0.f;
#pragma unroll
          for (int e = 0; e < 8; ++e) bias += gt[e * 32 + row] * b2[e * C_DIM + c];
          out[(size_t)(r0 + row) * C_DIM + c] = acc2[mt][r] + bias;
        }
      }
    }
  }
}

extern "C" void kernel_launch(void* const* d_in, const int* in_sizes, int n_in,
                              void* d_out, int out_size, void* d_ws, size_t ws_size,
                              hipStream_t stream) {
  const float* x  = (const float*)d_in[0];
  const float* W1 = (const float*)d_in[1];
  const float* b1 = (const float*)d_in[2];
  const float* W2 = (const float*)d_in[3];
  const float* b2 = (const float*)d_in[4];
  const float* Wg = (const float*)d_in[5];
  const float* bg = (const float*)d_in[6];
  float* out = (float*)d_out;

  unsigned short* W1bf = (unsigned short*)d_ws;
  unsigned short* W2bf = (unsigned short*)((char*)d_ws + (size_t)129 * 16 * 512 * 2);

  conv_w1<<<516, 256, 0, stream>>>(W1, Wg, W1bf);   // 129*16*64 slots
  conv_w2<<<128, 256, 0, stream>>>(W2, W2bf);       // 8*64*64 slots
  moe_main<<<2048, 512, 0, stream>>>(x, b1, b2, bg, W1bf, W2bf, out);
}

// Round 5
// 399.336 us; speedup vs baseline: 2.7355x; 1.0098x over previous
//
#include <hip/hip_runtime.h>

// MoE fused kernel, MI355X gfx950 — Round 8: Mtile=64, halved L2 weight traffic.
// Shapes: B=65536, D=512, C=101, E=8, H=256.
// out[b,c] = sum_{e,h} g[b,e]*relu(x@W1+b1)[b,e,h]*W2[e,h,c] + sum_e g[b,e]*b2[e,c]
// g = softmax(x@Wg+bg), gate logits folded into layer1 GEMM as cols 2048..2055.
//
// R7 post-mortem: 264us moe_main, MfmaUtil 28, VALU 20, HBM 6%, occ 45 — no
// pipe saturated; the binding resource is L2 weight re-read: every block reads
// W1bf 2.1MB + W2bf 0.45MB => 2048 blocks x 2.6MB = 5.2GB / 34.5TB/s = 151us
// floor (measured 264 => ~57% L2 util with barrier breaks). W1 traffic =
// 2.1MB * B/Mtile: Mtile is the only lever. R8 = R6 structure at Mtile=64:
// L2 -> 2.6GB (77us floor). LDS 130KB (xA 64K + hA 2-expert 64K + gt 2K) ->
// 1 block/CU, 8 waves; launch_bounds(512,2) cap 256 regs -> zero spill risk
// (tally ~110). Latency check at 2 waves/SIMD: 8 waves x 4KB prefetch in
// flight = 160B/cy sustainable >> 56B/cy L2 supply -> still BW-bound. Also
// merged conv_w1+conv_w2 into one launch (serialized before; also probes the
// constant ~140us bench-vs-moe gap).
// Decision rule: dur>220 & MfmaUtil<35 at occ 25 => latency-bound => R9 goes
// 1024-thread blocks (4 waves/SIMD, 16-way col split), same LDS.
//
// MFMA layouts (m89/m120-verified):
//   A: A[m][k], m=lane&15, k=(lane>>4)*8+j (j=0..7)
//   B: B[k][n], n=lane&15, k=(lane>>4)*8+j
//   C/D: col=lane&15, row=(lane>>4)*4+reg

typedef __attribute__((ext_vector_type(8))) short short8x;
typedef __attribute__((ext_vector_type(4))) float float4x;

#define C_DIM 101

__device__ __forceinline__ unsigned short f2bf(float f) {
  unsigned int u = __builtin_bit_cast(unsigned int, f);
  u += 0x7fffu + ((u >> 16) & 1u);     // round-to-nearest-even
  return (unsigned short)(u >> 16);
}

// ---- merged weight conversion (one launch, both convert in parallel)
// W1 (+Wg) -> bf16 B-frags: frag = ntile*16+kf ; elem = frag*512 + lane*8 + j
// W2       -> bf16 B-frags: frag = ntile*64+kf ; ntile 0..7, kf 0..63 (K=2048)
__global__ void conv_weights(const float* __restrict__ W1, const float* __restrict__ Wg,
                             const float* __restrict__ W2,
                             unsigned short* __restrict__ W1bf,
                             unsigned short* __restrict__ W2bf) {
  if (blockIdx.x < 516) {
    int s = blockIdx.x * blockDim.x + threadIdx.x;   // slot = frag*64 + lane
    int l = s & 63;
    int frag = s >> 6;
    int kf = frag & 15;
    int ntile = frag >> 4;
    int n = (ntile << 4) | (l & 15);
    int k = (kf << 5) | ((l >> 4) << 3);
    short8x v;
#pragma unroll
    for (int j = 0; j < 8; ++j) {
      int kk = k + j;
      float f;
      if (n < 2048)      f = W1[((size_t)(n >> 8) * 512 + kk) * 256 + (n & 255)];
      else if (n < 2056) f = Wg[(size_t)kk * 8 + (n - 2048)];
      else               f = 0.f;
      v[j] = (short)f2bf(f);
    }
    *(short8x*)(W1bf + (size_t)s * 8) = v;
  } else {
    int s = (blockIdx.x - 516) * blockDim.x + threadIdx.x;
    int l = s & 63;
    int frag = s >> 6;
    int kf = frag & 63;
    int ntile = frag >> 6;
    int c = (ntile << 4) | (l & 15);
    int k = (kf << 5) | ((l >> 4) << 3);
    short8x v;
#pragma unroll
    for (int j = 0; j < 8; ++j) {
      int kk = k + j;                       // e = kk>>8, h = kk&255
      float f = (c < C_DIM) ? W2[((size_t)(kk >> 8) * 256 + (kk & 255)) * C_DIM + c] : 0.f;
      v[j] = (short)f2bf(f);
    }
    *(short8x*)(W2bf + (size_t)s * 8) = v;
  }
}

// ---- fused main kernel: 64 rows/block, 512 threads (8 waves), 1 block/CU
__global__ __launch_bounds__(512, 2) void moe_main(
    const float* __restrict__ x, const float* __restrict__ b1,
    const float* __restrict__ b2, const float* __restrict__ bg,
    const unsigned short* __restrict__ W1bf, const unsigned short* __restrict__ W2bf,
    float* __restrict__ out) {
  __shared__ unsigned short xA[64 * 512];   // 64 KB: x A-frags [mt*16+kf][lane*8+j]
  __shared__ unsigned short hA[64 * 512];   // 64 KB: 2 experts x 32 h' A-frags
  __shared__ float gt[8 * 64];              //  2 KB: gates^T [e][row]
  float* graw = (float*)hA;                 // raw gate logits [64][8]; pre-loop only

  const int tid = threadIdx.x;
  const int w = tid >> 6;     // wave 0..7
  const int l = tid & 63;     // lane
  const int quad = l >> 4;
  const int p = l & 15;
  const int r0 = blockIdx.x * 64;

  // ---- stage x -> bf16 A-frag LDS (coalesced float4 x2 reads, b128 LDS writes)
#pragma unroll
  for (int it = 0; it < 8; ++it) {
    int g = tid + it * 512;            // m = g>>6 (0..63), k0 = (g&63)*8
    int m = g >> 6;
    int k0 = (g & 63) << 3;
    const float* src = x + (size_t)(r0 + m) * 512 + k0;
    float4 f0 = *(const float4*)src;
    float4 f1 = *(const float4*)(src + 4);
    short8x v;
    v[0] = (short)f2bf(f0.x); v[1] = (short)f2bf(f0.y);
    v[2] = (short)f2bf(f0.z); v[3] = (short)f2bf(f0.w);
    v[4] = (short)f2bf(f1.x); v[5] = (short)f2bf(f1.y);
    v[6] = (short)f2bf(f1.z); v[7] = (short)f2bf(f1.w);
    int mt = m >> 4;
    int kfrag = k0 >> 5;
    int lane = (((k0 >> 3) & 3) << 4) | (m & 15);
    *(short8x*)&xA[(size_t)(((mt << 4) | kfrag) * 64 + lane) * 8] = v;
  }
  __syncthreads();

  // ---- gate logits: waves 0..3 each do one 16-row tile x 16 gate cols (ntile 128)
  if (w < 4) {
    float4x acc = {0.f, 0.f, 0.f, 0.f};
#pragma unroll 2
    for (int kf = 0; kf < 16; ++kf) {
      short8x a = *(const short8x*)&xA[(size_t)((w * 16 + kf) * 64 + l) * 8];
      short8x b = *(const short8x*)(W1bf + ((size_t)(128 * 16 + kf) * 512 + l * 8));
      acc = __builtin_amdgcn_mfma_f32_16x16x32_bf16(a, b, acc, 0, 0, 0);
    }
    if (p < 8) {
      float bgv = bg[p];
#pragma unroll
      for (int r = 0; r < 4; ++r)
        graw[(w * 16 + quad * 4 + r) * 8 + p] = acc[r] + bgv;
    }
  }
  __syncthreads();
  // softmax over E=8 per row, fp32; write transposed gt[e][row]
  if (tid < 64) {
    float v[8], mx = -1e30f;
#pragma unroll
    for (int e = 0; e < 8; ++e) { v[e] = graw[tid * 8 + e]; mx = fmaxf(mx, v[e]); }
    float s = 0.f;
#pragma unroll
    for (int e = 0; e < 8; ++e) { v[e] = expf(v[e] - mx); s += v[e]; }
    float inv = 1.f / s;
#pragma unroll
    for (int e = 0; e < 8; ++e) gt[e * 64 + tid] = v[e] * inv;
  }
  __syncthreads();   // graw (hA alias) reads done before first hA write

  // ---- main loop: 4 iterations, 2 experts each. acc2 = ct-owned full-K sum.
  float4x zero = {0.f, 0.f, 0.f, 0.f};
  float4x acc2[4];                       // [mt]; wave w owns output col-tile ct=w (w<7)
  acc2[0] = zero; acc2[1] = zero; acc2[2] = zero; acc2[3] = zero;

  for (int it = 0; it < 4; ++it) {
#pragma unroll
    for (int eo = 0; eo < 2; ++eo) {
      const int e = it * 2 + eo;
      // layer1: wave w covers h-cols [e*256 + w*32, +32), all 64 rows.
      float4x acc1[4][2];                // [mt][nc]
#pragma unroll
      for (int mt = 0; mt < 4; ++mt) { acc1[mt][0] = zero; acc1[mt][1] = zero; }

      const unsigned short* __restrict__ bp =
          W1bf + ((size_t)(e * 16 + w * 2) * 16) * 512 + (size_t)l * 8;
      // nc stride = 16 frags * 512 = 8192 shorts; kf stride = 512 shorts
      short8x bA0 = *(const short8x*)(bp);
      short8x bA1 = *(const short8x*)(bp + 8192);
      short8x bB0, bB1;
#pragma unroll
      for (int kf = 0; kf < 16; kf += 2) {
        bB0 = *(const short8x*)(bp + (kf + 1) * 512);
        bB1 = *(const short8x*)(bp + 8192 + (kf + 1) * 512);
#pragma unroll
        for (int mt = 0; mt < 4; ++mt) {
          short8x a = *(const short8x*)&xA[(size_t)((mt * 16 + kf) * 64 + l) * 8];
          acc1[mt][0] = __builtin_amdgcn_mfma_f32_16x16x32_bf16(a, bA0, acc1[mt][0], 0, 0, 0);
          acc1[mt][1] = __builtin_amdgcn_mfma_f32_16x16x32_bf16(a, bA1, acc1[mt][1], 0, 0, 0);
        }
        if (kf + 2 < 16) {
          bA0 = *(const short8x*)(bp + (kf + 2) * 512);
          bA1 = *(const short8x*)(bp + 8192 + (kf + 2) * 512);
        }
#pragma unroll
        for (int mt = 0; mt < 4; ++mt) {
          short8x a = *(const short8x*)&xA[(size_t)((mt * 16 + kf + 1) * 64 + l) * 8];
          acc1[mt][0] = __builtin_amdgcn_mfma_f32_16x16x32_bf16(a, bB0, acc1[mt][0], 0, 0, 0);
          acc1[mt][1] = __builtin_amdgcn_mfma_f32_16x16x32_bf16(a, bB1, acc1[mt][1], 0, 0, 0);
        }
      }

      if (eo == 0) __syncthreads();      // BAR1: prev iteration's layer2 hA reads done

      // epilogue: +b1, relu, *gate(e), bf16 -> hA[eo] (C->A transpose)
      // wave w's 32 cols form exactly K-frag kf2=w; frag = eo*32 + w*4 + mt
      float4x gv0 = *(const float4x*)&gt[e * 64 + 0  + quad * 4];
      float4x gv1 = *(const float4x*)&gt[e * 64 + 16 + quad * 4];
      float4x gv2 = *(const float4x*)&gt[e * 64 + 32 + quad * 4];
      float4x gv3 = *(const float4x*)&gt[e * 64 + 48 + quad * 4];
#pragma unroll
      for (int nc = 0; nc < 2; ++nc) {
        int cw = w * 32 + nc * 16 + p;   // col within expert tile (0..255)
        float b1v = b1[e * 256 + cw];
        int jj = p & 7;
        int ldbase = ((nc * 2 + (p >> 3)) << 4);   // (koff>>3)*16, koff = nc*16+p
#pragma unroll
        for (int mt = 0; mt < 4; ++mt) {
          float4x gv = (mt == 0) ? gv0 : (mt == 1) ? gv1 : (mt == 2) ? gv2 : gv3;
#pragma unroll
          for (int r = 0; r < 4; ++r) {
            float hv = fmaxf(acc1[mt][nc][r] + b1v, 0.f) * gv[r];
            hA[(size_t)((eo * 32 + w * 4 + mt) * 512) + (ldbase + quad * 4 + r) * 8 + jj] =
                f2bf(hv);
          }
        }
      }
    }
    __syncthreads();                     // BAR2: both experts' h' published

    // layer2: wave w (<7) accumulates ct=w over both experts' K=512
    if (w < 7) {
      const unsigned short* __restrict__ bp2 =
          W2bf + ((size_t)(w * 64 + it * 16)) * 512 + (size_t)l * 8;
      // W2 frag = w*64 + (it*2+eo)*8 + kf2 -> offset (eo*8+kf2)*512 from bp2
#pragma unroll
      for (int eo = 0; eo < 2; ++eo) {
#pragma unroll
        for (int kf2 = 0; kf2 < 8; ++kf2) {
          short8x b = *(const short8x*)(bp2 + (size_t)(eo * 8 + kf2) * 512);
#pragma unroll
          for (int mt = 0; mt < 4; ++mt) {
            short8x a = *(const short8x*)&hA[(size_t)((eo * 32 + kf2 * 4 + mt) * 64 + l) * 8];
            acc2[mt] = __builtin_amdgcn_mfma_f32_16x16x32_bf16(a, b, acc2[mt], 0, 0, 0);
          }
        }
      }
    }
  }

  // ---- epilogue: + gate-weighted b2, store. No cross-wave reduction.
  if (w < 7) {
    int c = w * 16 + p;
    if (c < C_DIM) {
#pragma unroll
      for (int mt = 0; mt < 4; ++mt) {
#pragma unroll
        for (int r = 0; r < 4; ++r) {
          int row = mt * 16 + quad * 4 + r;
          float bias = 0.f;
#pragma unroll
          for (int e = 0; e < 8; ++e) bias += gt[e * 64 + row] * b2[e * C_DIM + c];
          out[(size_t)(r0 + row) * C_DIM + c] = acc2[mt][r] + bias;
        }
      }
    }
  }
}

extern "C" void kernel_launch(void* const* d_in, const int* in_sizes, int n_in,
                              void* d_out, int out_size, void* d_ws, size_t ws_size,
                              hipStream_t stream) {
  const float* x  = (const float*)d_in[0];
  const float* W1 = (const float*)d_in[1];
  const float* b1 = (const float*)d_in[2];
  const float* W2 = (const float*)d_in[3];
  const float* b2 = (const float*)d_in[4];
  const float* Wg = (const float*)d_in[5];
  const float* bg = (const float*)d_in[6];
  float* out = (float*)d_out;

  unsigned short* W1bf = (unsigned short*)d_ws;
  unsigned short* W2bf = (unsigned short*)((char*)d_ws + (size_t)129 * 16 * 512 * 2);

  conv_weights<<<644, 256, 0, stream>>>(W1, Wg, W2, W1bf, W2bf);  // 516 + 128 blocks
  moe_main<<<1024, 512, 0, stream>>>(x, b1, b2, bg, W1bf, W2bf, out);
}